// Round 8
// baseline (275.874 us; speedup 1.0000x reference)
//
#include <hip/hip_runtime.h>

typedef __attribute__((ext_vector_type(4))) float float4v;

#define NBLK  1024
#define NITER 8

// Persistent 1024 blocks x 256 threads (4 waves), 8 windows each, double-
// buffered LDS staging via global_load_lds. 4 blocks/CU co-resident ->
// 16 waves/CU = 4 waves/SIMD (2x round 7's 2/SIMD; LDS 32 KB caps at 5).
// Thread layout: wave = variant v; lane = tok(4) x idx(16); thread owns 16
// channels (half of head h=idx>>1). Full-head dot via one shfl_xor(s,1).
// Staging: wave w stages tensor w (4 rows = 4 loads/wave) -> ledger vmcnt(4)
// keeps ONLY the newest prefetch loads outstanding (round-6 rule: never
// leave stores in the kept window).
// Epilogue: full-line stores via transpose through each wave's OWN staging
// region of buf[cur] (4 KB/wave, XOR-involution layout = conflict-balanced).
// Safe because: post-compute barrier orders all compute reads before scratch
// writes; region is DMA-overwritten only by the owner wave (program order).
__global__ __launch_bounds__(256, 4) void cattn_kernel(
    const float* __restrict__ rr, const float* __restrict__ gg,
    const float* __restrict__ bb, const float* __restrict__ ii,
    const float* __restrict__ w0, const float* __restrict__ b0,
    const float* __restrict__ w1, const float* __restrict__ b1,
    const float* __restrict__ w2, const float* __restrict__ b2,
    const float* __restrict__ w3, const float* __restrict__ b3,
    float* __restrict__ out)
{
    __shared__ float sm[2 * 4096];           // two 16 KB window buffers
    float4v* SM4 = (float4v*)sm;

    const int t   = threadIdx.x;
    const int wvi = t >> 6;                  // wave 0..3 = variant v
    const int l   = t & 63;
    const int c4g = l ^ ((l >> 3) & 7);      // swizzled global chunk for staging

    const int v   = wvi;
    const int tok = l >> 4;                  // query token 0..3
    const int idx = l & 15;                  // 16 lanes = 256 ch, 16 ch each
    const int h   = idx >> 1;                // head 0..7 (pair idx, idx^1)
    const int kvt = (v == 3) ? 1 : (v + 1);  // kv tensor: g,b,ir,g (K==V)

    // hoisted LN params, transposed indexing: store j covers chunks j*16+idx
    // = channels j*64 + idx*4 .. +4
    const float* lwr = (v & 2) ? ((v & 1) ? w3 : w2) : ((v & 1) ? w1 : w0);
    const float* lbr = (v & 2) ? ((v & 1) ? b3 : b2) : ((v & 1) ? b1 : b0);
    float4v wp[4], bp[4];
    #pragma unroll
    for (int j = 0; j < 4; ++j) {
        wp[j] = *(const float4v*)(lwr + j * 64 + idx * 4);
        bp[j] = *(const float4v*)(lbr + j * 64 + idx * 4);
    }

    const float* srcs[4] = { rr, gg, bb, ii };

    // stage one window: wave w loads tensor w's 4 token-rows (4 x 1 KB)
    auto issue = [&](int buf, int wid) {
        const int bi  = wid >> 10;
        const int rem = wid & 1023;
        const int y0  = (rem >> 5) << 1;
        const int x0  = (rem & 31) << 1;
        #pragma unroll
        for (int kk = 0; kk < 4; ++kk) {     // kk = token = dy*2+dx
            const float* g = srcs[wvi]
                + (((size_t)(bi * 64 + y0 + (kk >> 1))) * 64 + (size_t)(x0 + (kk & 1))) * 256
                + (size_t)(c4g << 2);
            float* ldst = sm + buf * 4096 + (((wvi << 2) | kk) << 8);
            __builtin_amdgcn_global_load_lds(
                (const __attribute__((address_space(1))) void*)g,
                (__attribute__((address_space(3))) void*)ldst,
                16, 0, 0);
        }
    };

    int wid = blockIdx.x;                    // 8 windows: wid + k*1024
    issue(0, wid);
    int cur = 0;

    #pragma unroll 2
    for (int it = 0; it < NITER; ++it, wid += NBLK) {
        // issue prefetch FIRST, then wait keeping exactly those 4 loads
        // outstanding: drains current staging + param loads + prev stores.
        if (it < NITER - 1) {
            issue(cur ^ 1, wid + NBLK);
            asm volatile("s_waitcnt vmcnt(4)" ::: "memory");
        } else {
            asm volatile("s_waitcnt vmcnt(0)" ::: "memory");
        }
        __builtin_amdgcn_s_barrier();        // all waves' staging arrived
        __builtin_amdgcn_sched_barrier(0);

        // ---------- compute window `wid` from buf[cur] ----------
        const int bb4  = cur << 10;                        // buf offset, chunks
        const int qrow = bb4 + v * 256 + tok * 64;
        const int krow = bb4 + kvt * 256;

        // q fragment: global chunks idx*4+r of row (v,tok); LDS slot = gc^h
        float4v q[4];
        #pragma unroll
        for (int r = 0; r < 4; ++r) q[r] = SM4[qrow + ((idx * 4 + r) ^ h)];

        // pass 1: partial scores over own 16 ch, then combine with partner
        float s[4] = {0.f, 0.f, 0.f, 0.f};
        #pragma unroll
        for (int r = 0; r < 4; ++r) {
            #pragma unroll
            for (int tk = 0; tk < 4; ++tk) {
                float4v c = SM4[krow + tk * 64 + ((idx * 4 + r) ^ h)];
                s[tk] += q[r][0]*c[0] + q[r][1]*c[1] + q[r][2]*c[2] + q[r][3]*c[3];
            }
        }
        #pragma unroll
        for (int tk = 0; tk < 4; ++tk) {
            s[tk] += __shfl_xor(s[tk], 1, 64);             // full 32-ch dot
            s[tk] *= 0.17677669529663687f;                 // 1/sqrt(32)
        }

        // softmax over 4
        float mx = fmaxf(fmaxf(s[0], s[1]), fmaxf(s[2], s[3]));
        float p[4];
        #pragma unroll
        for (int tk = 0; tk < 4; ++tk) p[tk] = __expf(s[tk] - mx);
        const float inv = 1.f / (p[0] + p[1] + p[2] + p[3]);
        #pragma unroll
        for (int tk = 0; tk < 4; ++tk) p[tk] *= inv;

        // pass 2: o = residual(q) + P·V  (V chunks == K chunks)
        float o[16];
        #pragma unroll
        for (int r = 0; r < 4; ++r)
            #pragma unroll
            for (int e = 0; e < 4; ++e) o[r * 4 + e] = q[r][e];
        #pragma unroll
        for (int tk = 0; tk < 4; ++tk) {
            const float pj = p[tk];
            #pragma unroll
            for (int r = 0; r < 4; ++r) {
                float4v c = SM4[krow + tk * 64 + ((idx * 4 + r) ^ h)];
                #pragma unroll
                for (int e = 0; e < 4; ++e) o[r * 4 + e] += pj * c[e];
            }
        }

        // LayerNorm over 256 ch: reduce across the 16 lanes of the tok-group
        float sum = 0.f, sq = 0.f;
        #pragma unroll
        for (int c = 0; c < 16; ++c) { sum += o[c]; sq += o[c] * o[c]; }
        #pragma unroll
        for (int off = 1; off < 16; off <<= 1) {
            sum += __shfl_xor(sum, off, 64);
            sq  += __shfl_xor(sq,  off, 64);
        }
        const float mu  = sum * (1.f / 256.f);
        const float var = sq * (1.f / 256.f) - mu * mu;
        const float rs  = rsqrtf(var + 1e-5f);

        // ---- epilogue: transpose through OWN staging region of buf[cur] ----
        __builtin_amdgcn_s_barrier();        // all compute reads of buf[cur] done
        __builtin_amdgcn_sched_barrier(0);

        const int sbase = bb4 + v * 256 + tok * 64;   // own region, own tok row
        #pragma unroll
        for (int r = 0; r < 4; ++r) {
            float4v c;
            #pragma unroll
            for (int e = 0; e < 4; ++e) c[e] = o[r * 4 + e];
            SM4[sbase + ((idx * 4 + r) ^ h)] = c;     // involution layout
        }
        asm volatile("s_waitcnt lgkmcnt(0)" ::: "memory");
        __builtin_amdgcn_sched_barrier(0);

        const int bi  = wid >> 10;
        const int rem = wid & 1023;
        const int y0  = (rem >> 5) << 1;
        const int x0  = (rem & 31) << 1;
        const int dy  = tok >> 1, dx = tok & 1;
        float* op = out
            + ((size_t)(bi * 64 + y0 + dy) * 64 + (size_t)(x0 + dx)) * 1024
            + (size_t)(v << 8);

        #pragma unroll
        for (int j = 0; j < 4; ++j) {
            // read back global chunk j*16+idx -> 16 lanes = 256 B contiguous
            const int gc2 = j * 16 + idx;
            float4v c = SM4[sbase + (gc2 ^ ((gc2 >> 3) & 7))];
            float4v ov;
            #pragma unroll
            for (int e = 0; e < 4; ++e)
                ov[e] = (c[e] - mu) * rs * wp[j][e] + bp[j][e];
            *(float4v*)(op + j * 64 + idx * 4) = ov;
        }

        cur ^= 1;
    }
}

extern "C" void kernel_launch(void* const* d_in, const int* in_sizes, int n_in,
                              void* d_out, int out_size, void* d_ws, size_t ws_size,
                              hipStream_t stream) {
    (void)in_sizes; (void)n_in; (void)d_ws; (void)ws_size; (void)out_size;
    const float* rr = (const float*)d_in[0];
    const float* gg = (const float*)d_in[1];
    const float* bb = (const float*)d_in[2];
    const float* ii = (const float*)d_in[3];
    const float* w0 = (const float*)d_in[4];
    const float* b0 = (const float*)d_in[5];
    const float* w1 = (const float*)d_in[6];
    const float* b1 = (const float*)d_in[7];
    const float* w2 = (const float*)d_in[8];
    const float* b2 = (const float*)d_in[9];
    const float* w3 = (const float*)d_in[10];
    const float* b3 = (const float*)d_in[11];
    float* out = (float*)d_out;

    cattn_kernel<<<NBLK, 256, 0, stream>>>(rr, gg, bb, ii,
                                           w0, b0, w1, b1, w2, b2, w3, b3, out);
}